// Round 1
// baseline (1794.305 us; speedup 1.0000x reference)
//
#include <hip/hip_runtime.h>
#include <math.h>

// Problem: CrossAttention  B=32, S=1024, D_MODEL=48, NUM_HEADS=3, D_K=16
// Outputs: H [32,1024,48] then A [32,3,1024,1024], concatenated flat fp32.

#define NROWS   32768      // B*S
#define HW_SZ   1572864L   // 96*1024*16 floats per Q/K/V/Hh buffer

__device__ __forceinline__ void load16(const float* __restrict__ p, float* r) {
    float4 a = ((const float4*)p)[0];
    float4 b = ((const float4*)p)[1];
    float4 c = ((const float4*)p)[2];
    float4 d = ((const float4*)p)[3];
    r[0]=a.x;  r[1]=a.y;  r[2]=a.z;  r[3]=a.w;
    r[4]=b.x;  r[5]=b.y;  r[6]=b.z;  r[7]=b.w;
    r[8]=c.x;  r[9]=c.y;  r[10]=c.z; r[11]=c.w;
    r[12]=d.x; r[13]=d.y; r[14]=d.z; r[15]=d.w;
}

// ---------------- Kernel 1: fused Q/K/V projections ----------------
// Block = 192 threads = 4 rows x 48 out-channels. Writes [B,H,S,16] layout.
__global__ __launch_bounds__(192) void proj_qkv(
    const float* __restrict__ Xq, const float* __restrict__ Xk, const float* __restrict__ Xv,
    const float* __restrict__ Wq, const float* __restrict__ bq,
    const float* __restrict__ Wk, const float* __restrict__ bk,
    const float* __restrict__ Wv, const float* __restrict__ bv,
    float* __restrict__ Qo, float* __restrict__ Ko, float* __restrict__ Vo)
{
    __shared__ float Wls[3][48][49];   // +1 pad breaks bank conflicts
    __shared__ float bls[3][48];
    __shared__ float Xls[3][4][48];
    const int t = threadIdx.x;

    for (int f = t; f < 3*48*48; f += 192) {
        int m = f / 2304, rem = f % 2304, r = rem / 48, c = rem % 48;
        const float* W = (m == 0) ? Wq : ((m == 1) ? Wk : Wv);
        Wls[m][r][c] = W[r*48 + c];
    }
    if (t < 144) {
        int m = t / 48, c = t % 48;
        const float* bb = (m == 0) ? bq : ((m == 1) ? bk : bv);
        bls[m][c] = bb[c];
    }
    const long row0 = (long)blockIdx.x * 4;
    for (int f = t; f < 576; f += 192) {
        int m = f / 192, rem = f % 192, r = rem / 48, c = rem % 48;
        const float* X = (m == 0) ? Xq : ((m == 1) ? Xk : Xv);
        Xls[m][r][c] = X[(row0 + r)*48 + c];
    }
    __syncthreads();

    const int r = t / 48, j = t % 48;
    float aq = bls[0][j], ak = bls[1][j], av = bls[2][j];
#pragma unroll
    for (int i = 0; i < 48; i++) {
        aq += Xls[0][r][i] * Wls[0][j][i];
        ak += Xls[1][r][i] * Wls[1][j][i];
        av += Xls[2][r][i] * Wls[2][j][i];
    }
    const long srow = row0 + r;
    const long b = srow >> 10, sp = srow & 1023;
    const int  h = j >> 4, d = j & 15;
    const long idx = (((b*3 + h) << 10) + sp)*16 + d;
    Qo[idx] = aq; Ko[idx] = ak; Vo[idx] = av;
}

// ---------------- Kernel 2: fused attention ----------------
// Block = 256 threads handles (bh, 16-query tile). 16 lanes per q-row.
// Lane kl owns k = 64*j + 4*kl + i  (j=0..15, i=0..3)  -> 64 scores in VGPRs.
__global__ __launch_bounds__(256) void attn(
    const float* __restrict__ Q, const float* __restrict__ K, const float* __restrict__ V,
    float* __restrict__ A, float* __restrict__ Hh)
{
    const int blk = blockIdx.x;
    const int bh  = blk >> 6;      // 0..95
    const int qt  = blk & 63;
    const int t   = threadIdx.x;
    const int qg  = t >> 4;        // 0..15 query in tile
    const int kl  = t & 15;        // 0..15 k-lane

    const long base = (long)bh * 1024 * 16;
    const int  q    = qt * 16 + qg;

    // q row, pre-scaled by 1/sqrt(d_k) = 0.25
    float qv[16];
    load16(Q + base + (long)q * 16, qv);
#pragma unroll
    for (int d = 0; d < 16; d++) qv[d] *= 0.25f;

    // ---- scores ----
    float s[64];
    const float* Kb = K + base;
#pragma unroll
    for (int j = 0; j < 16; j++) {
#pragma unroll
        for (int i = 0; i < 4; i++) {
            const int k = j*64 + kl*4 + i;
            float kr[16];
            load16(Kb + (long)k * 16, kr);
            float acc = 0.f;
#pragma unroll
            for (int d = 0; d < 16; d++) acc += qv[d] * kr[d];
            s[j*4 + i] = acc;
        }
    }

    // ---- softmax across the 16-lane q-group ----
    float m = -1e30f;
#pragma unroll
    for (int x = 0; x < 64; x++) m = fmaxf(m, s[x]);
#pragma unroll
    for (int mask = 1; mask < 16; mask <<= 1) m = fmaxf(m, __shfl_xor(m, mask, 16));
    float l = 0.f;
#pragma unroll
    for (int x = 0; x < 64; x++) { s[x] = __expf(s[x] - m); l += s[x]; }
#pragma unroll
    for (int mask = 1; mask < 16; mask <<= 1) l += __shfl_xor(l, mask, 16);
    const float inv = 1.0f / l;
#pragma unroll
    for (int x = 0; x < 64; x++) s[x] *= inv;

    // ---- write A (coalesced float4: q-group covers 64 consecutive k per j) ----
    float* Arow = A + ((long)bh * 1024 + q) * 1024;
#pragma unroll
    for (int j = 0; j < 16; j++) {
        float4 p4 = make_float4(s[j*4+0], s[j*4+1], s[j*4+2], s[j*4+3]);
        *((float4*)(Arow + j*64 + kl*4)) = p4;
    }

    // ---- PV ----
    float o[16];
#pragma unroll
    for (int d = 0; d < 16; d++) o[d] = 0.f;
    const float* Vb = V + base;
#pragma unroll
    for (int j = 0; j < 16; j++) {
#pragma unroll
        for (int i = 0; i < 4; i++) {
            const int k = j*64 + kl*4 + i;
            const float p = s[j*4 + i];
            float vr[16];
            load16(Vb + (long)k * 16, vr);
#pragma unroll
            for (int d = 0; d < 16; d++) o[d] += p * vr[d];
        }
    }
#pragma unroll
    for (int mask = 1; mask < 16; mask <<= 1) {
#pragma unroll
        for (int d = 0; d < 16; d++) o[d] += __shfl_xor(o[d], mask, 16);
    }
    // lane kl writes component kl -> 16 consecutive floats per q-row
    Hh[base + (long)q * 16 + kl] = o[kl];
}

// ---------------- Kernel 3: output projection ----------------
__global__ __launch_bounds__(192) void proj_out(
    const float* __restrict__ Hh, const float* __restrict__ Wh, const float* __restrict__ bhp,
    float* __restrict__ Hout)
{
    __shared__ float Wls[48][49];
    __shared__ float bls[48];
    __shared__ float Hls[4][48];
    const int t = threadIdx.x;

    for (int f = t; f < 2304; f += 192) Wls[f/48][f%48] = Wh[f];
    if (t < 48) bls[t] = bhp[t];
    const long row0 = (long)blockIdx.x * 4;
    {
        int r = t / 48, i = t % 48;
        long srow = row0 + r;
        long b = srow >> 10, sp = srow & 1023;
        Hls[r][i] = Hh[(((b*3 + (i >> 4)) << 10) + sp)*16 + (i & 15)];
    }
    __syncthreads();

    const int r = t / 48, j = t % 48;
    float acc = bls[j];
#pragma unroll
    for (int i = 0; i < 48; i++) acc += Hls[r][i] * Wls[j][i];
    Hout[(row0 + r)*48 + j] = acc;
}

extern "C" void kernel_launch(void* const* d_in, const int* in_sizes, int n_in,
                              void* d_out, int out_size, void* d_ws, size_t ws_size,
                              hipStream_t stream) {
    const float* Xq = (const float*)d_in[0];
    const float* Xk = (const float*)d_in[1];
    const float* Xv = (const float*)d_in[2];
    const float* Wq = (const float*)d_in[3];
    const float* bq = (const float*)d_in[4];
    const float* Wk = (const float*)d_in[5];
    const float* bk = (const float*)d_in[6];
    const float* Wv = (const float*)d_in[7];
    const float* bv = (const float*)d_in[8];
    const float* Wh = (const float*)d_in[9];
    const float* bh = (const float*)d_in[10];

    float* out = (float*)d_out;
    float* Hout = out;                    // [32,1024,48]
    float* Aout = out + HW_SZ;            // [32,3,1024,1024]

    float* ws = (float*)d_ws;
    float* Qw = ws;
    float* Kw = ws + HW_SZ;
    float* Vw = ws + 2*HW_SZ;
    float* Hw = ws + 3*HW_SZ;

    proj_qkv<<<NROWS/4, 192, 0, stream>>>(Xq, Xk, Xv, Wq, bq, Wk, bk, Wv, bv, Qw, Kw, Vw);
    attn<<<96*64, 256, 0, stream>>>(Qw, Kw, Vw, Aout, Hw);
    proj_out<<<NROWS/4, 192, 0, stream>>>(Hw, Wh, bh, Hout);
}

// Round 2
// 889.446 us; speedup vs baseline: 2.0173x; 2.0173x over previous
//
#include <hip/hip_runtime.h>
#include <math.h>

// CrossAttention  B=32, S=1024, D_MODEL=48, NUM_HEADS=3, D_K=16
// Outputs: H [32,1024,48] ++ A [32,3,1024,1024], fp32.

#define NROWS   32768      // B*S
#define HW_SZ   1572864L   // 96*1024*16 floats per Q/K/V/Hh buffer
#define PITCH   20         // LDS row pitch (floats): 2-way bank conflict = free

__device__ __forceinline__ void load16(const float* __restrict__ p, float* r) {
    float4 a = ((const float4*)p)[0];
    float4 b = ((const float4*)p)[1];
    float4 c = ((const float4*)p)[2];
    float4 d = ((const float4*)p)[3];
    r[0]=a.x;  r[1]=a.y;  r[2]=a.z;  r[3]=a.w;
    r[4]=b.x;  r[5]=b.y;  r[6]=b.z;  r[7]=b.w;
    r[8]=c.x;  r[9]=c.y;  r[10]=c.z; r[11]=c.w;
    r[12]=d.x; r[13]=d.y; r[14]=d.z; r[15]=d.w;
}

// ---------------- Kernel 1: fused Q/K/V projections ----------------
// Block = 192 threads, 32 rows/block (8 groups of 4 rows). Weights staged once.
__global__ __launch_bounds__(192) void proj_qkv(
    const float* __restrict__ Xq, const float* __restrict__ Xk, const float* __restrict__ Xv,
    const float* __restrict__ Wq, const float* __restrict__ bq,
    const float* __restrict__ Wk, const float* __restrict__ bk,
    const float* __restrict__ Wv, const float* __restrict__ bv,
    float* __restrict__ Qo, float* __restrict__ Ko, float* __restrict__ Vo)
{
    __shared__ float Wls[3][48][49];
    __shared__ float bls[3][48];
    __shared__ float Xls[3][32][48];
    const int t = threadIdx.x;

    for (int f = t; f < 3*48*48; f += 192) {
        int m = f / 2304, rem = f % 2304, r = rem / 48, c = rem % 48;
        const float* W = (m == 0) ? Wq : ((m == 1) ? Wk : Wv);
        Wls[m][r][c] = W[r*48 + c];
    }
    if (t < 144) {
        int m = t / 48, c = t % 48;
        const float* bb = (m == 0) ? bq : ((m == 1) ? bk : bv);
        bls[m][c] = bb[c];
    }
    const long row0 = (long)blockIdx.x * 32;
    // Stage 3*32*48 floats = 1152 float4; 6 per thread, coalesced.
    for (int f = t; f < 1152; f += 192) {
        int m = f / 384, ff = f % 384, r = ff / 12, p = ff % 12;
        const float* X = (m == 0) ? Xq : ((m == 1) ? Xk : Xv);
        float4 v = *(const float4*)(X + (row0 + r)*48 + p*4);
        *(float4*)&Xls[m][r][p*4] = v;
    }
    __syncthreads();

    const int rb = t / 48, j = t % 48;
    const int h = j >> 4, d = j & 15;
#pragma unroll
    for (int rl = 0; rl < 8; rl++) {
        const int r = rl*4 + rb;
        float aq = bls[0][j], ak = bls[1][j], av = bls[2][j];
#pragma unroll
        for (int i = 0; i < 48; i++) {
            aq += Xls[0][r][i] * Wls[0][j][i];
            ak += Xls[1][r][i] * Wls[1][j][i];
            av += Xls[2][r][i] * Wls[2][j][i];
        }
        const long srow = row0 + r;
        const long b = srow >> 10, sp = srow & 1023;
        const long idx = (((b*3 + h) << 10) + sp)*16 + d;
        Qo[idx] = aq; Ko[idx] = ak; Vo[idx] = av;
    }
}

// ---------------- Kernel 2: fused attention ----------------
// Block = 256 threads = (bh, 16-query tile); 16 lanes per q-row.
// Lane kl owns k with k % 16 == kl. K/V staged in LDS (256-row chunks, pitch 20).
__global__ __launch_bounds__(256) void attn(
    const float* __restrict__ Q, const float* __restrict__ K, const float* __restrict__ V,
    float* __restrict__ A, float* __restrict__ Hh)
{
    __shared__ float KV[256 * PITCH];   // 20 KB, reused for K then V

    const int blk = blockIdx.x;
    const int bh  = blk >> 6;      // 0..95
    const int qt  = blk & 63;
    const int t   = threadIdx.x;
    const int qg  = t >> 4;        // 0..15 query in tile
    const int kl  = t & 15;        // 0..15 k-lane

    const long base = (long)bh * 1024 * 16;
    const int  q    = qt * 16 + qg;

    float qv[16];
    load16(Q + base + (long)q * 16, qv);
#pragma unroll
    for (int d = 0; d < 16; d++) qv[d] *= 0.25f;   // 1/sqrt(16)

    const float* Kb = K + base;
    const float* Vb = V + base;

    // ---- Phase 1: scores (4 chunks of 256 k-rows) ----
    float s[64];
#pragma unroll 1
    for (int c = 0; c < 4; c++) {
        __syncthreads();
#pragma unroll
        for (int i = 0; i < 4; i++) {
            int f = t + 256*i;           // 0..1023
            int r = f >> 2, p = f & 3;
            float4 v = ((const float4*)Kb)[(c*256 + r)*4 + p];
            *(float4*)&KV[r*PITCH + p*4] = v;
        }
        __syncthreads();
#pragma unroll
        for (int i = 0; i < 16; i++) {
            const float* row = &KV[(i*16 + kl) * PITCH];
            float acc = 0.f;
#pragma unroll
            for (int d = 0; d < 16; d++) acc += qv[d] * row[d];
            s[c*16 + i] = acc;
        }
    }

    // ---- softmax across the 16-lane q-group ----
    float m = -1e30f;
#pragma unroll
    for (int x = 0; x < 64; x++) m = fmaxf(m, s[x]);
#pragma unroll
    for (int mask = 1; mask < 16; mask <<= 1) m = fmaxf(m, __shfl_xor(m, mask, 16));
    float l = 0.f;
#pragma unroll
    for (int x = 0; x < 64; x++) { s[x] = __expf(s[x] - m); l += s[x]; }
#pragma unroll
    for (int mask = 1; mask < 16; mask <<= 1) l += __shfl_xor(l, mask, 16);
    const float inv = 1.0f / l;
#pragma unroll
    for (int x = 0; x < 64; x++) s[x] *= inv;

    // ---- Phase 2: write A + accumulate PV (V chunks through same LDS) ----
    float o[16];
#pragma unroll
    for (int d = 0; d < 16; d++) o[d] = 0.f;
    float* Arow = A + ((long)bh * 1024 + q) * 1024;

#pragma unroll 1
    for (int c = 0; c < 4; c++) {
        __syncthreads();
#pragma unroll
        for (int i = 0; i < 4; i++) {
            int f = t + 256*i;
            int r = f >> 2, p = f & 3;
            float4 v = ((const float4*)Vb)[(c*256 + r)*4 + p];
            *(float4*)&KV[r*PITCH + p*4] = v;
        }
        __syncthreads();
#pragma unroll
        for (int i = 0; i < 16; i++) {
            const int kloc = i*16 + kl;
            const float p = s[c*16 + i];
            Arow[c*256 + kloc] = p;
            const float* row = &KV[kloc * PITCH];
#pragma unroll
            for (int d = 0; d < 16; d++) o[d] += p * row[d];
        }
    }

#pragma unroll
    for (int mask = 1; mask < 16; mask <<= 1) {
#pragma unroll
        for (int d = 0; d < 16; d++) o[d] += __shfl_xor(o[d], mask, 16);
    }
    Hh[base + (long)q * 16 + kl] = o[kl];
}

// ---------------- Kernel 3: output projection ----------------
__global__ __launch_bounds__(192) void proj_out(
    const float* __restrict__ Hh, const float* __restrict__ Wh, const float* __restrict__ bhp,
    float* __restrict__ Hout)
{
    __shared__ float Wls[48][49];
    __shared__ float bls[48];
    __shared__ float Hls[32][48];
    const int t = threadIdx.x;

    for (int f = t; f < 2304; f += 192) Wls[f/48][f%48] = Wh[f];
    if (t < 48) bls[t] = bhp[t];
    const long row0 = (long)blockIdx.x * 32;
    for (int f = t; f < 1536; f += 192) {
        int r = f / 48, col = f % 48;
        long srow = row0 + r;
        long b = srow >> 10, sp = srow & 1023;
        Hls[r][col] = Hh[(((b*3 + (col >> 4)) << 10) + sp)*16 + (col & 15)];
    }
    __syncthreads();

    const int rb = t / 48, j = t % 48;
#pragma unroll
    for (int rl = 0; rl < 8; rl++) {
        const int r = rl*4 + rb;
        float acc = bls[j];
#pragma unroll
        for (int i = 0; i < 48; i++) acc += Hls[r][i] * Wls[j][i];
        Hout[(row0 + r)*48 + j] = acc;
    }
}

extern "C" void kernel_launch(void* const* d_in, const int* in_sizes, int n_in,
                              void* d_out, int out_size, void* d_ws, size_t ws_size,
                              hipStream_t stream) {
    const float* Xq = (const float*)d_in[0];
    const float* Xk = (const float*)d_in[1];
    const float* Xv = (const float*)d_in[2];
    const float* Wq = (const float*)d_in[3];
    const float* bq = (const float*)d_in[4];
    const float* Wk = (const float*)d_in[5];
    const float* bk = (const float*)d_in[6];
    const float* Wv = (const float*)d_in[7];
    const float* bv = (const float*)d_in[8];
    const float* Wh = (const float*)d_in[9];
    const float* bh = (const float*)d_in[10];

    float* out = (float*)d_out;
    float* Hout = out;                    // [32,1024,48]
    float* Aout = out + HW_SZ;            // [32,3,1024,1024]

    float* ws = (float*)d_ws;
    float* Qw = ws;
    float* Kw = ws + HW_SZ;
    float* Vw = ws + 2*HW_SZ;
    float* Hw = ws + 3*HW_SZ;

    proj_qkv<<<NROWS/32, 192, 0, stream>>>(Xq, Xk, Xv, Wq, bq, Wk, bk, Wv, bv, Qw, Kw, Vw);
    attn<<<96*64, 256, 0, stream>>>(Qw, Kw, Vw, Aout, Hw);
    proj_out<<<NROWS/32, 192, 0, stream>>>(Hw, Wh, bh, Hout);
}